// Round 12
// baseline (5896.294 us; speedup 1.0000x reference)
//
#include <hip/hip_runtime.h>
#include <cstdint>
#include <cstddef>
#include <string.h>

typedef __bf16 bf16;
typedef bf16 bf16x4 __attribute__((ext_vector_type(4)));
typedef bf16 bf16x8 __attribute__((ext_vector_type(8)));
typedef float f32x4 __attribute__((ext_vector_type(4)));
typedef unsigned u32x4v __attribute__((ext_vector_type(4)));
typedef unsigned long long u64;

#define B_   64
#define T_   512
#define I_   1024
#define H_   1024
#define BT_  32768
#define NBL  64    // lstm blocks
#define NJ   16    // hidden units per lstm block

// ---- ws layout (bytes) ----
// WS_XBF doubles as the h RING after phase 1 (xbf is dead once k_gemm_xg ran):
// slot t (t=1..512) at WS_XBF + (t-1)*131072, sentinel-filled 0xFF (bf16 NaN).
#define WS_XBF   ((size_t)0)              // x bf16 [32768][1024] / h ring [512][64][1024]
#define WS_WXP   ((size_t)67108864)       // Wx^T bf16 [4096][1024]             : 8388608
#define WS_WHP   ((size_t)75497472)       // Wh packed bf16 [64][128][64][8]    : 8388608
#define WS_XG    ((size_t)83886080)       // xg bf16 [512][64][64][64]          : 268435456
#define WS_HB    ((size_t)352321536)      // h(0) bf16 [64][1024] zeros         : 131072
#define WS_NEED  ((size_t)352600064)

#define GLD_LDS16(gptr, lptr) \
  __builtin_amdgcn_global_load_lds((const __attribute__((address_space(1))) void*)(gptr), \
                                   (__attribute__((address_space(3))) void*)(lptr), 16, 0, 0)

__device__ __forceinline__ float sigmoidf_(float x) { return 1.0f / (1.0f + __expf(-x)); }
// branch-free tanh: 1 - 2/(e^{2x}+1); saturates correctly for |x| large (no NaN).
__device__ __forceinline__ float tanhf_(float x) { float e = __expf(2.0f * x); return 1.0f - 2.0f / (e + 1.0f); }
__device__ __forceinline__ float lo2f(unsigned u) { unsigned v = u << 16; float f; memcpy(&f, &v, 4); return f; }
__device__ __forceinline__ float hi2f(unsigned u) { unsigned v = u & 0xffff0000u; float f; memcpy(&f, &v, 4); return f; }
__device__ __forceinline__ unsigned short b2s(bf16 h) { unsigned short s; memcpy(&s, &h, 2); return s; }

// sentinel check: 4 chunks (16 dwords) all != 0xFFFFFFFF
__device__ __forceinline__ bool chk4(const bf16x8* af, int base) {
  bool ok = true;
#pragma unroll
  for (int i = 0; i < 4; ++i) {
    u32x4v d = __builtin_bit_cast(u32x4v, af[base + i]);
    ok = ok & (d[0] != 0xFFFFFFFFu) & (d[1] != 0xFFFFFFFFu) &
         (d[2] != 0xFFFFFFFFu) & (d[3] != 0xFFFFFFFFu);
  }
  return ok;
}

// ---------------- pack kernels ----------------

__global__ __launch_bounds__(256) void k_cvt_x(const float4* __restrict__ in,
                                               bf16* __restrict__ out, int n4) {
  int i = blockIdx.x * blockDim.x + threadIdx.x;
  int stride = gridDim.x * blockDim.x;
  for (; i < n4; i += stride) {
    float4 v = in[i];
    bf16x4 r = { (bf16)v.x, (bf16)v.y, (bf16)v.z, (bf16)v.w };
    *(bf16x4*)(out + (size_t)i * 4) = r;
  }
}

// Wx^T: wxp[(gate*1024 + n)][k] = W[k][n]   (32x32 LDS tile transpose)
__global__ __launch_bounds__(256) void k_pack_wx(const float* __restrict__ W,
                                                 bf16* __restrict__ wxp, int gate) {
  __shared__ bf16 tile[32][33];
  int bx = blockIdx.x & 31, by = blockIdx.x >> 5;
  int tx = threadIdx.x & 31, ty = threadIdx.x >> 5;
  int k0 = by * 32, n0 = bx * 32;
  for (int r = 0; r < 32; r += 8)
    tile[ty + r][tx] = (bf16)W[(size_t)(k0 + ty + r) * H_ + n0 + tx];
  __syncthreads();
  for (int r = 0; r < 32; r += 8)
    wxp[(size_t)(gate * H_ + n0 + ty + r) * I_ + k0 + tx] = tile[tx][ty + r];
}

// Wh packed GATE-MAJOR: whp[blk][k>>3][gate*16 + (u&15)][k&7] = W[k][u]
__global__ __launch_bounds__(256) void k_pack_wh(const float* __restrict__ W,
                                                 bf16* __restrict__ whp, int gate) {
  __shared__ bf16 tile[32][33];
  int bx = blockIdx.x & 31, by = blockIdx.x >> 5;
  int tx = threadIdx.x & 31, ty = threadIdx.x >> 5;
  int k0 = by * 32, u0 = bx * 32;
  for (int r = 0; r < 32; r += 8)
    tile[ty + r][tx] = (bf16)W[(size_t)(k0 + ty + r) * H_ + u0 + tx];
  __syncthreads();
  for (int r = 0; r < 32; r += 8) {
    int u = u0 + ty + r;
    int k = k0 + tx;
    size_t addr = ((size_t)(u >> 4) * 128 + (k >> 3)) * 512 +
                  (size_t)(gate * 16 + (u & 15)) * 8 + (k & 7);
    whp[addr] = tile[tx][ty + r];
  }
}

// ---------------- phase 1: xg = x @ Wx  (bf16 MFMA, m97-style) ----------------
// xg: xg[t][blk][b][c],  blk = u>>4, c = gate*16 + (u&15)
__global__ __launch_bounds__(256) void k_gemm_xg(const bf16* __restrict__ A,
                                                 const bf16* __restrict__ Bt,
                                                 bf16* __restrict__ xg) {
  __shared__ bf16 As[128 * 64];
  __shared__ bf16 Bs[128 * 64];
  int bid = blockIdx.x;
  int bm = bid >> 5, bn = bid & 31;
  int m0 = bm * 128, n0 = bn * 128;
  int tid = threadIdx.x, lane = tid & 63, w = tid >> 6;
  int lr = lane & 15, lk = lane >> 4;
  int sr = lane >> 3, sk = (lane & 7) * 8;
  int wm = (w >> 1) * 64, wn = (w & 1) * 64;
  f32x4 acc[4][4] = {};

  for (int k0 = 0; k0 < 1024; k0 += 64) {
    __syncthreads();
    for (int i = 0; i < 4; ++i) {
      int idx = w * 4 + i;
      const bf16* ga = A + (size_t)(m0 + idx * 8 + sr) * 1024 + k0 + sk;
      GLD_LDS16(ga, &As[idx * 512]);
      const bf16* gb = Bt + (size_t)(n0 + idx * 8 + sr) * 1024 + k0 + sk;
      GLD_LDS16(gb, &Bs[idx * 512]);
    }
    asm volatile("s_waitcnt vmcnt(0)" ::: "memory");
    __syncthreads();
#pragma unroll
    for (int kk = 0; kk < 64; kk += 32) {
      bf16x8 af[4], bfr[4];
#pragma unroll
      for (int i = 0; i < 4; ++i)
        af[i] = *(const bf16x8*)&As[(wm + i * 16 + lr) * 64 + kk + lk * 8];
#pragma unroll
      for (int j = 0; j < 4; ++j)
        bfr[j] = *(const bf16x8*)&Bs[(wn + j * 16 + lr) * 64 + kk + lk * 8];
#pragma unroll
      for (int i = 0; i < 4; ++i)
#pragma unroll
        for (int j = 0; j < 4; ++j)
          acc[i][j] = __builtin_amdgcn_mfma_f32_16x16x32_bf16(af[i], bfr[j], acc[i][j], 0, 0, 0);
    }
  }
#pragma unroll
  for (int i = 0; i < 4; ++i) {
#pragma unroll
    for (int j = 0; j < 4; ++j) {
      int n = n0 + wn + j * 16 + lr;
      int u = n & 1023, g = n >> 10;
      int blk = u >> 4, c = g * 16 + (u & 15);
      int mb = m0 + wm + i * 16 + lk * 4;
#pragma unroll
      for (int r = 0; r < 4; ++r) {
        int m = mb + r;
        int t = m & 511, bb = m >> 9;
        xg[(((size_t)t * NBL + blk) * B_ + bb) * 64 + c] = (bf16)acc[i][j][r];
      }
    }
  }
}

// ---------------- phase 2: persistent cooperative LSTM scan (R7 + data-as-flag) ----------------
// 64 blocks x 512 threads (8 waves, 2/SIMD). Wave = (wm rowgrp16, kh K-half).
// Data-as-flag: per-step h slots in a sentinel ring (0xFF = bf16 NaN, impossible for
// h = o*tanh(c)). Publishes are dword-atomic (2 units/thread). Consumers poll the DATA:
// pipelined A-loads + per-group sentinel checks gate the MFMAs; own-sector check (own
// block's 8 dwords/row) preserves the gl-overwrite guarantee (pair publish => pair gl-read
// done). No drain, no flags, no 3rd sync. gl exchange keeps R7's 2 syncs (pair-scoped data;
// cross-step barrier mixing is a safe rendezvous).
__global__ __launch_bounds__(512) void k_lstm(const bf16* __restrict__ xg,
                                              const bf16* __restrict__ whp,
                                              const char* __restrict__ hb0,  // h(0) zeros
                                              char* ring,                    // [512][64][1024] bf16
                                              float* __restrict__ out,
                                              const float* __restrict__ bii, const float* __restrict__ bhi,
                                              const float* __restrict__ bif, const float* __restrict__ bhf,
                                              const float* __restrict__ big, const float* __restrict__ bhg,
                                              const float* __restrict__ bio, const float* __restrict__ bho) {
  __shared__ bf16 whl[65536];          // 128 KB: [k>>3][c][k&7], c = g*16+u
  __shared__ float gl[64 * 65];        // kh0 partials, padded rows
  int blk = blockIdx.x;
  int tid = threadIdx.x;
  int lane = tid & 63, w = tid >> 6;
  int lr = lane & 15, lk = lane >> 4;
  int wm = (w >> 1) * 16;   // row-group (16 batch rows)
  int kh = w & 1;           // K half

  {  // stage Wh slice: 128KB contiguous
    const bf16* src = whp + (size_t)blk * 65536;
#pragma unroll
    for (int i = 0; i < 16; ++i)
      *(bf16x8*)&whl[(size_t)(i * 512 + tid) * 8] = *(const bf16x8*)&src[(size_t)(i * 512 + tid) * 8];
  }

  // elementwise mapping: thread -> (batch b, unit pair 2*eu2, 2*eu2+1)
  int eu2 = tid & 7, b = tid >> 3;
  int u0g = blk * NJ + eu2 * 2, u1g = u0g + 1;
  float bi0 = bii[u0g] + bhi[u0g], bi1 = bii[u1g] + bhi[u1g];
  float bf0 = bif[u0g] + bhf[u0g], bf1 = bif[u1g] + bhf[u1g];
  float bg0 = big[u0g] + bhg[u0g], bg1 = big[u1g] + bhg[u1g];
  float bo0 = bio[u0g] + bho[u0g], bo1 = bio[u1g] + bho[u1g];
  float c0 = 0.f, c1 = 0.f;

  __syncthreads();  // whl ready

  for (int t = 0; t < T_; ++t) {
    const char* hsrc = (t == 0) ? hb0 : ring + (size_t)(t - 1) * 131072;
    const char* hbase = hsrc + (size_t)(wm + lr) * 2048 + (size_t)kh * 1024 + (size_t)lk * 16;
    const char* osec  = hsrc + (size_t)(wm + lr) * 2048 + (size_t)blk * 32 + (size_t)lk * 8;
    const char* xgb = (const char*)xg + (((size_t)t * NBL + blk) * B_ + b) * 128 + eu2 * 4;

    bf16x8 af[16];
    u64 osv;
    unsigned xv[4];
    f32x4 acc[4];
    int tries = 0;
    bool ok;

  restart:
    acc[0] = (f32x4){}; acc[1] = (f32x4){}; acc[2] = (f32x4){}; acc[3] = (f32x4){};
    // issue: 16 A-chunks + 1 own-sector + 4 xg  (21 outstanding)
#pragma unroll
    for (int i = 0; i < 16; ++i)
      asm volatile("global_load_dwordx4 %0, %1, off sc0 sc1"
                   : "=v"(af[i]) : "v"(hbase + (size_t)i * 64));
    asm volatile("global_load_dwordx2 %0, %1, off sc0 sc1" : "=v"(osv) : "v"(osec));
#pragma unroll
    for (int g = 0; g < 4; ++g)
      asm volatile("global_load_dword %0, %1, off" : "=v"(xv[g]) : "v"(xgb + (size_t)g * 32));

#define MFMA_GRP(G)                                                                        \
    _Pragma("unroll")                                                                      \
    for (int ii = 0; ii < 4; ++ii) {                                                       \
      int i = (G) * 4 + ii;                                                                \
      int kg = kh * 64 + i * 4 + lk;                                                       \
      _Pragma("unroll")                                                                    \
      for (int nt = 0; nt < 4; ++nt) {                                                     \
        bf16x8 bb = *(const bf16x8*)&whl[(kg * 64 + nt * 16 + lr) * 8];                    \
        acc[nt] = __builtin_amdgcn_mfma_f32_16x16x32_bf16(af[i], bb, acc[nt], 0, 0, 0);    \
      }                                                                                    \
    }
    asm volatile("s_waitcnt vmcnt(17)" ::: "memory");
    __builtin_amdgcn_sched_barrier(0);
    ok = chk4(af, 0);
    if (!__all((int)ok)) { asm volatile("s_waitcnt vmcnt(0)" ::: "memory"); if (++tries < 200000) goto restart; }
    MFMA_GRP(0)
    asm volatile("s_waitcnt vmcnt(13)" ::: "memory");
    __builtin_amdgcn_sched_barrier(0);
    ok = chk4(af, 4);
    if (!__all((int)ok)) { asm volatile("s_waitcnt vmcnt(0)" ::: "memory"); if (++tries < 200000) goto restart; }
    MFMA_GRP(1)
    asm volatile("s_waitcnt vmcnt(9)" ::: "memory");
    __builtin_amdgcn_sched_barrier(0);
    ok = chk4(af, 8);
    if (!__all((int)ok)) { asm volatile("s_waitcnt vmcnt(0)" ::: "memory"); if (++tries < 200000) goto restart; }
    MFMA_GRP(2)
    asm volatile("s_waitcnt vmcnt(5)" ::: "memory");
    __builtin_amdgcn_sched_barrier(0);
    ok = chk4(af, 12);
    if (!__all((int)ok)) { asm volatile("s_waitcnt vmcnt(0)" ::: "memory"); if (++tries < 200000) goto restart; }
    MFMA_GRP(3)
#undef MFMA_GRP
    asm volatile("s_waitcnt vmcnt(0)" ::: "memory");   // osec + xg landed
    __builtin_amdgcn_sched_barrier(0);
    {
      unsigned o0 = (unsigned)osv, o1 = (unsigned)(osv >> 32);
      ok = (o0 != 0xFFFFFFFFu) & (o1 != 0xFFFFFFFFu);
      if (!__all((int)ok)) { if (++tries < 200000) goto restart; }
    }

    // ---- kh0: deposit partials in gl ----
    int grow = wm + lk * 4;
    if (kh == 0) {
#pragma unroll
      for (int nt = 0; nt < 4; ++nt)
#pragma unroll
        for (int r = 0; r < 4; ++r)
          gl[(grow + r) * 65 + nt * 16 + lr] = acc[nt][r];
    }
    __syncthreads();   // sync#1: kh0 partials visible
    if (kh == 1) {
#pragma unroll
      for (int nt = 0; nt < 4; ++nt)
#pragma unroll
        for (int r = 0; r < 4; ++r)
          gl[(grow + r) * 65 + nt * 16 + lr] += acc[nt][r];
    }
    __syncthreads();   // sync#2: full gate pre-activations ready

    // ---- gates + state update ----
    int gb = b * 65 + eu2 * 2;
    float gi0 = gl[gb]          + lo2f(xv[0]) + bi0;
    float gi1 = gl[gb + 1]      + hi2f(xv[0]) + bi1;
    float gf0 = gl[gb + 16]     + lo2f(xv[1]) + bf0;
    float gf1 = gl[gb + 17]     + hi2f(xv[1]) + bf1;
    float gg0 = gl[gb + 32]     + lo2f(xv[2]) + bg0;
    float gg1 = gl[gb + 33]     + hi2f(xv[2]) + bg1;
    float go0 = gl[gb + 48]     + lo2f(xv[3]) + bo0;
    float go1 = gl[gb + 49]     + hi2f(xv[3]) + bo1;
    c0 = sigmoidf_(gf0) * c0 + sigmoidf_(gi0) * tanhf_(gg0);
    c1 = sigmoidf_(gf1) * c1 + sigmoidf_(gi1) * tanhf_(gg1);
    float hv0 = sigmoidf_(go0) * tanhf_(c0);
    float hv1 = sigmoidf_(go1) * tanhf_(c1);

    if (t == T_ - 1) {
      out[(size_t)b * H_ + u0g] = hv0;
      out[(size_t)b * H_ + u1g] = hv1;
      out[(size_t)B_ * H_ + b * H_ + u0g] = c0;
      out[(size_t)B_ * H_ + b * H_ + u1g] = c1;
      break;
    }

    // ---- publish h(t+1) into ring slot t: dword-atomic (2 units), 32B sectors.
    // No drain, no flag, no 3rd sync — the data IS the flag.
    unsigned hp = (unsigned)b2s((bf16)hv0) | ((unsigned)b2s((bf16)hv1) << 16);
    unsigned* hw = (unsigned*)(ring + (size_t)t * 131072);
    __hip_atomic_store(hw + b * 512 + blk * 8 + eu2, hp, __ATOMIC_RELAXED, __HIP_MEMORY_SCOPE_AGENT);
  }
}

// ---------------- launcher ----------------

extern "C" void kernel_launch(void* const* d_in, const int* in_sizes, int n_in,
                              void* d_out, int out_size, void* d_ws, size_t ws_size,
                              hipStream_t stream) {
  if (ws_size < WS_NEED) return;

  const float* x = (const float*)d_in[0];
  const float* W_ii = (const float*)d_in[1];
  const float* W_hi = (const float*)d_in[2];
  const float* W_if = (const float*)d_in[3];
  const float* W_hf = (const float*)d_in[4];
  const float* W_ig = (const float*)d_in[5];
  const float* W_hg = (const float*)d_in[6];
  const float* W_io = (const float*)d_in[7];
  const float* W_ho = (const float*)d_in[8];
  const float* b_ii = (const float*)d_in[9];
  const float* b_hi = (const float*)d_in[10];
  const float* b_if = (const float*)d_in[11];
  const float* b_hf = (const float*)d_in[12];
  const float* b_ig = (const float*)d_in[13];
  const float* b_hg = (const float*)d_in[14];
  const float* b_io = (const float*)d_in[15];
  const float* b_ho = (const float*)d_in[16];

  char* ws = (char*)d_ws;
  bf16* xbf = (bf16*)(ws + WS_XBF);
  bf16* wxp = (bf16*)(ws + WS_WXP);
  bf16* whp = (bf16*)(ws + WS_WHP);
  bf16* xgp = (bf16*)(ws + WS_XG);
  char* hb0 = ws + WS_HB;
  char* ring = ws + WS_XBF;   // reuses xbf region after phase 1
  float* outp = (float*)d_out;

  // h(0) = zeros
  hipMemsetAsync(hb0, 0, 131072, stream);

  // pack
  k_cvt_x<<<2048, 256, 0, stream>>>((const float4*)x, xbf, BT_ * I_ / 4);
  const float* wx_g[4] = {W_ii, W_if, W_ig, W_io};
  const float* wh_g[4] = {W_hi, W_hf, W_hg, W_ho};
  for (int g = 0; g < 4; ++g) {
    k_pack_wx<<<1024, 256, 0, stream>>>(wx_g[g], wxp, g);
    k_pack_wh<<<1024, 256, 0, stream>>>(wh_g[g], whp, g);
  }

  // phase 1 GEMM (last reader of xbf)
  k_gemm_xg<<<dim3(256 * 32), 256, 0, stream>>>(xbf, wxp, xgp);

  // sentinel-fill the h ring (0xFF bytes = bf16 NaN) — stream-ordered after k_gemm_xg
  hipMemsetAsync(ring, 0xFF, (size_t)512 * 131072, stream);

  // phase 2 cooperative scan
  void* args[] = {
      (void*)&xgp, (void*)&whp, (void*)&hb0, (void*)&ring, (void*)&outp,
      (void*)&b_ii, (void*)&b_hi, (void*)&b_if, (void*)&b_hf,
      (void*)&b_ig, (void*)&b_hg, (void*)&b_io, (void*)&b_ho};
  hipLaunchCooperativeKernel((const void*)k_lstm, dim3(NBL), dim3(512), args, 0, stream);
}